// Round 8
// baseline (28.837 us; speedup 1.0000x reference)
//
#include <hip/hip_runtime.h>

// PDE2DReservoir — spectral Green's function, ONE dispatch, ZERO grid sync.
// measured[m] = sum_j vals_j * K(m - p_j); K = fixed 127-radius stencil,
// 128-periodic == free-space (support radius <= 63).
// Every block is fully self-sufficient (rounds 3/5/6: cross-XCD sync ~50us;
// round 7: each graph-node boundary ~10-20us — so: no boundaries at all).
//   - each thread recomputes vals for exactly the injections it scans
//   - each block redundantly builds the 65x65 folded weighted Khat (Horner)
//   - per hit: K(a,c) = sum_wx sum_wy khf[wy][wx] cos(wx*ta) cos(wy*tc),
//     cos(wx*ta) via Chebyshev recurrence (no LDS gather, broadcast reads)

#define N_INJ   4096
#define N_MEAS  4096
#define ND      128
#define NM      65               // folded modes 0..64
#define STEPS   64
#define WRAP_M  4095
#define NB      256              // independent blocks
#define NT      512
#define MPB     16               // measurements per block (N_MEAS / NB)
#define HC      512              // hit-list capacity (expected ~63/block)
#define KST     68               // khf row stride (floats)
#define CHUNK   32               // hits processed per dot-phase pass

__global__ __launch_bounds__(NT) void fused_all(const float* __restrict__ u_t,
                                                const float* __restrict__ scales,
                                                const int* __restrict__ dims,
                                                const int* __restrict__ iix,
                                                const int* __restrict__ iiy,
                                                const int* __restrict__ mix,
                                                const int* __restrict__ miy,
                                                float* __restrict__ out) {
    const int b = blockIdx.x;
    const int t = threadIdx.x;

    __shared__ float ctab[ND];          // cos(2*pi*i/128)
    __shared__ float coeff[STEPS];      // DT * sin(2*pi*s/64)
    __shared__ float khf[NM * KST];     // weighted Khat, [wx][wy], symmetric
    __shared__ int   hitP[HC];
    __shared__ float hitV[HC];
    __shared__ float part[NT / 64][CHUNK];
    __shared__ float smacc[MPB];
    __shared__ int   nhit;

    if (t < ND)    ctab[t]  = cosf(0.049087385212340517f * (float)t);
    if (t < STEPS) coeff[t] = 0.001f * sinf(0.09817477042468103f * (float)t);
    if (t < MPB)   smacc[t] = 0.f;
    if (t == 0)    nhit = 0;

    // block-uniform measurement coords (scalarized loads)
    int mx[MPB], my[MPB];
#pragma unroll
    for (int i = 0; i < MPB; ++i) {
        mx[i] = mix[b * MPB + i];
        my[i] = miy[b * MPB + i];
    }
    __syncthreads();

    // ---- build folded weighted Khat: 9 entries per thread, Horner deg 63 ----
    {
        float hh[9], lam[9];
#pragma unroll
        for (int k = 0; k < 9; ++k) {
            int e = t + NT * k; if (e >= NM * NM) e = NM * NM - 1;
            const int wx = e / NM, wy = e - wx * NM;
            lam[k] = 0.9f + 0.05f * (ctab[wx] + ctab[wy]);
            hh[k]  = coeff[0];
        }
#pragma unroll 9
        for (int s = 1; s < STEPS; ++s) {
            const float cs = coeff[s];
#pragma unroll
            for (int k = 0; k < 9; ++k) hh[k] = fmaf(hh[k], lam[k], cs);
        }
#pragma unroll
        for (int k = 0; k < 9; ++k) {
            const int e = t + NT * k;
            if (e < NM * NM) {
                const int wx = e / NM, wy = e - wx * NM;
                const float w = ((wx == 0 || wx == 64) ? 1.f : 2.f)
                              * ((wy == 0 || wy == 64) ? 1.f : 2.f) * (1.f / 16384.f);
                khf[wx * KST + wy] = hh[k] * w;
            }
        }
    }
    __syncthreads();

    // ---- scan: vals computed inline; hits -> LDS list ----
    for (int jj = 0; jj < N_INJ / NT; ++jj) {
        const int j   = jj * NT + t;
        const float v = scales[j] * u_t[dims[j]];
        const int ix  = iix[j];
        const int iy  = iiy[j];
#pragma unroll
        for (int i = 0; i < MPB; ++i) {
            const int a  = (mx[i] - ix) & WRAP_M;
            const int c  = (my[i] - iy) & WRAP_M;
            const int ax = min(a, 4096 - a);
            const int ay = min(c, 4096 - c);
            if (max(ax, ay) < 64) {
                const int pos = atomicAdd(&nhit, 1);
                if (pos < HC) {
                    hitP[pos] = ((a & 127) << 11) | ((c & 127) << 4) | i;
                    hitV[pos] = v;
                }
            }
        }
    }
    __syncthreads();

    // ---- dense per-hit 2-D cosine dots, 32 hits per pass ----
    const int nh   = min(nhit, HC);
    const int wave = t >> 6;
    const int lane = t & 63;
    const int wyg  = t >> 5;                  // 0..15: wy subset {wyg,+16,+32,+48}
    const int wy4  = (wyg == 0) ? 64 : 0;     // extra row wy=64 handled by wyg==0

    for (int base = 0; base < nh; base += CHUNK) {
        const int h = base + (t & (CHUNK - 1));
        int pk = 0;
        if (h < nh) pk = hitP[h];
        const int am = (pk >> 11) & 127;
        const int cm = (pk >> 4) & 127;

        float a0 = 0.f, a1 = 0.f, a2 = 0.f, a3 = 0.f, a4 = 0.f;
        const float c1  = ctab[am];
        const float tc1 = 2.f * c1;
        float cwm = c1;                        // cos(-theta) = cos(theta)
        float cw  = 1.f;                       // cos(0)
#pragma unroll 5
        for (int wx = 0; wx < NM; ++wx) {
            a0 = fmaf(khf[(wyg)      * KST + wx], cw, a0);
            a1 = fmaf(khf[(wyg + 16) * KST + wx], cw, a1);
            a2 = fmaf(khf[(wyg + 32) * KST + wx], cw, a2);
            a3 = fmaf(khf[(wyg + 48) * KST + wx], cw, a3);
            a4 = fmaf(khf[wy4        * KST + wx], cw, a4);
            const float nx = fmaf(tc1, cw, -cwm);
            cwm = cw; cw = nx;
        }
        float partial = a0 * ctab[(wyg * cm) & 127]
                      + a1 * ctab[((wyg + 16) * cm) & 127]
                      + a2 * ctab[((wyg + 32) * cm) & 127]
                      + a3 * ctab[((wyg + 48) * cm) & 127];
        if (wyg == 0) partial += a4 * ctab[(64 * cm) & 127];

        partial += __shfl_xor(partial, 32, 64);     // fold lane l with l^32
        if (lane < CHUNK) part[wave][lane] = partial;
        __syncthreads();
        if (t < CHUNK) {
            const int hh = base + t;
            if (hh < nh) {
                float K = 0.f;
#pragma unroll
                for (int w = 0; w < NT / 64; ++w) K += part[w][t];
                atomicAdd(&smacc[hitP[hh] & 15], hitV[hh] * K);
            }
        }
        __syncthreads();
    }

    if (t < MPB) out[b * MPB + t] = smacc[t];
}

extern "C" void kernel_launch(void* const* d_in, const int* in_sizes, int n_in,
                              void* d_out, int out_size, void* d_ws, size_t ws_size,
                              hipStream_t stream) {
    const float* u_t        = (const float*)d_in[0];
    const float* inj_scales = (const float*)d_in[1];
    const int*   inj_dims   = (const int*)d_in[2];
    const int*   inj_ix     = (const int*)d_in[3];
    const int*   inj_iy     = (const int*)d_in[4];
    const int*   meas_ix    = (const int*)d_in[5];
    const int*   meas_iy    = (const int*)d_in[6];
    float*       out        = (float*)d_out;

    hipLaunchKernelGGL(fused_all, dim3(NB), dim3(NT), 0, stream,
                       u_t, inj_scales, inj_dims, inj_ix, inj_iy,
                       meas_ix, meas_iy, out);
}

// Round 9
// 27.332 us; speedup vs baseline: 1.0551x; 1.0551x over previous
//
#include <hip/hip_runtime.h>

// PDE2DReservoir — spectral Green's function, ONE dispatch, ZERO grid sync.
// measured[m] = sum_j vals_j * K(m - p_j); K = fixed 127-radius stencil,
// 128-periodic == free-space (support radius <= 63).
// Round-8 lesson: the per-hit dot phase was LDS-pipe bound (5 ds_read per
// wx-iter per thread, ~2600 LDS wave-instrs/CU/pass through ONE LDS pipe).
// This version: 32 row-groups x 2 rows, 4 hits per thread sharing each khf
// read -> ~1100 LDS instrs/CU, single pass for <=64 hits.

#define N_INJ   4096
#define N_MEAS  4096
#define ND      128
#define NM      65               // folded modes 0..64
#define STEPS   64
#define WRAP_M  4095
#define NB      256              // independent blocks
#define NT      512
#define MPB     16               // measurements per block
#define HC      512              // hit-list capacity (expected ~63/block)
#define KST     68               // khf row stride (floats)
#define HPP     64               // hits per dot pass

__global__ __launch_bounds__(NT) void fused_all(const float* __restrict__ u_t,
                                                const float* __restrict__ scales,
                                                const int* __restrict__ dims,
                                                const int* __restrict__ iix,
                                                const int* __restrict__ iiy,
                                                const int* __restrict__ mix,
                                                const int* __restrict__ miy,
                                                float* __restrict__ out) {
    const int b = blockIdx.x;
    const int t = threadIdx.x;

    __shared__ float ctab[ND];          // cos(2*pi*i/128)
    __shared__ float coeff[STEPS];      // DT * sin(2*pi*s/64)
    __shared__ float khf[NM * KST];     // weighted Khat, [wy][wx] (symmetric)
    __shared__ int   hitP[HC];
    __shared__ float hitV[HC];
    __shared__ float part[NT / 64][HPP];
    __shared__ float smacc[MPB];
    __shared__ int   nhit;

    if (t < ND)    ctab[t]  = cosf(0.049087385212340517f * (float)t);
    if (t < STEPS) coeff[t] = 0.001f * sinf(0.09817477042468103f * (float)t);
    if (t < MPB)   smacc[t] = 0.f;
    if (t == 0)    nhit = 0;

    int mx[MPB], my[MPB];
#pragma unroll
    for (int i = 0; i < MPB; ++i) {
        mx[i] = mix[b * MPB + i];
        my[i] = miy[b * MPB + i];
    }
    __syncthreads();

    // ---- build folded weighted Khat: 9 entries per thread, Horner deg 63 ----
    {
        float hh[9], lam[9];
#pragma unroll
        for (int k = 0; k < 9; ++k) {
            int e = t + NT * k; if (e >= NM * NM) e = NM * NM - 1;
            const int wx = e / NM, wy = e - wx * NM;
            lam[k] = 0.9f + 0.05f * (ctab[wx] + ctab[wy]);
            hh[k]  = coeff[0];
        }
#pragma unroll 9
        for (int s = 1; s < STEPS; ++s) {
            const float cs = coeff[s];
#pragma unroll
            for (int k = 0; k < 9; ++k) hh[k] = fmaf(hh[k], lam[k], cs);
        }
#pragma unroll
        for (int k = 0; k < 9; ++k) {
            const int e = t + NT * k;
            if (e < NM * NM) {
                const int wx = e / NM, wy = e - wx * NM;
                const float w = ((wx == 0 || wx == 64) ? 1.f : 2.f)
                              * ((wy == 0 || wy == 64) ? 1.f : 2.f) * (1.f / 16384.f);
                khf[wx * KST + wy] = hh[k] * w;   // symmetric: [wy][wx] too
            }
        }
    }
    __syncthreads();

    // ---- scan: vals inline; fused range test; hits -> LDS list ----
    for (int jj = 0; jj < N_INJ / NT; ++jj) {
        const int j   = jj * NT + t;
        const float v = scales[j] * u_t[dims[j]];
        const int ix  = iix[j];
        const int iy  = iiy[j];
#pragma unroll
        for (int i = 0; i < MPB; ++i) {
            const int a = (mx[i] - ix) & WRAP_M;
            const int c = (my[i] - iy) & WRAP_M;
            // |dx|<64 <=> (a+63) mod 4096 < 127  (likewise dy)
            if ((((a + 63) & WRAP_M) < 127) && (((c + 63) & WRAP_M) < 127)) {
                const int pos = atomicAdd(&nhit, 1);
                if (pos < HC) {
                    hitP[pos] = ((a & 127) << 11) | ((c & 127) << 4) | i;
                    hitV[pos] = v;
                }
            }
        }
    }
    __syncthreads();

    // ---- per-hit 2-D cosine dots: 32 groups x 2 rows, 4 hits/thread ----
    const int nh  = min(nhit, HC);
    const int grp = t >> 4;              // 0..31: rows {grp, grp+32} (+64 if 0)
    const int hq  = t & 15;              // hit-quartet id
    const int r0  = grp;
    const int r1  = grp + 32;
    const bool g0 = (grp == 0);

    for (int base = 0; base < nh; base += HPP) {
        int   am[4], cm[4];
        float tc[4], cw[4], cwm[4];
#pragma unroll
        for (int i = 0; i < 4; ++i) {
            const int h  = base + hq + 16 * i;
            const int pk = (h < nh) ? hitP[h] : 0;
            am[i] = (pk >> 11) & 127;
            cm[i] = (pk >> 4) & 127;
            const float c1 = ctab[am[i]];
            tc[i] = 2.f * c1;  cw[i] = 1.f;  cwm[i] = c1;
        }
        float a0[4] = {0.f, 0.f, 0.f, 0.f};
        float a1[4] = {0.f, 0.f, 0.f, 0.f};
        float a2[4] = {0.f, 0.f, 0.f, 0.f};
#pragma unroll 5
        for (int wx = 0; wx < NM; ++wx) {
            const float k0 = khf[r0 * KST + wx];
            const float k1 = khf[r1 * KST + wx];
            float k2 = 0.f;
            if (g0) k2 = khf[64 * KST + wx];
#pragma unroll
            for (int i = 0; i < 4; ++i) {
                a0[i] = fmaf(k0, cw[i], a0[i]);
                a1[i] = fmaf(k1, cw[i], a1[i]);
                a2[i] = fmaf(k2, cw[i], a2[i]);
                const float nx = fmaf(tc[i], cw[i], -cwm[i]);
                cwm[i] = cw[i];  cw[i] = nx;
            }
        }
        float p0, p1, p2, p3;
        {
            float pr[4];
#pragma unroll
            for (int i = 0; i < 4; ++i) {
                float pi = a0[i] * ctab[(r0 * cm[i]) & 127]
                         + a1[i] * ctab[(r1 * cm[i]) & 127]
                         + a2[i] * ctab[(cm[i] << 6) & 127];
                pi += __shfl_xor(pi, 16, 64);       // fold grp bit 0
                pi += __shfl_xor(pi, 32, 64);       // fold grp bit 1
                pr[i] = pi;
            }
            p0 = pr[0]; p1 = pr[1]; p2 = pr[2]; p3 = pr[3];
        }
        if ((t & 63) < 16)
            *reinterpret_cast<float4*>(&part[t >> 6][(t & 15) << 2]) =
                float4{p0, p1, p2, p3};
        __syncthreads();
        if (t < HPP) {
            const int hit = base + (t >> 2) + ((t & 3) << 4);
            if (hit < nh) {
                float K = 0.f;
#pragma unroll
                for (int w = 0; w < NT / 64; ++w) K += part[w][t];
                atomicAdd(&smacc[hitP[hit] & 15], hitV[hit] * K);
            }
        }
        __syncthreads();
    }

    if (t < MPB) out[b * MPB + t] = smacc[t];
}

extern "C" void kernel_launch(void* const* d_in, const int* in_sizes, int n_in,
                              void* d_out, int out_size, void* d_ws, size_t ws_size,
                              hipStream_t stream) {
    const float* u_t        = (const float*)d_in[0];
    const float* inj_scales = (const float*)d_in[1];
    const int*   inj_dims   = (const int*)d_in[2];
    const int*   inj_ix     = (const int*)d_in[3];
    const int*   inj_iy     = (const int*)d_in[4];
    const int*   meas_ix    = (const int*)d_in[5];
    const int*   meas_iy    = (const int*)d_in[6];
    float*       out        = (float*)d_out;

    hipLaunchKernelGGL(fused_all, dim3(NB), dim3(NT), 0, stream,
                       u_t, inj_scales, inj_dims, inj_ix, inj_iy,
                       meas_ix, meas_iy, out);
}

// Round 10
// 20.916 us; speedup vs baseline: 1.3787x; 1.3067x over previous
//
#include <hip/hip_runtime.h>

// PDE2DReservoir — spectral Green's function + spatial binning, 2 dispatches.
// measured[m] = sum_j vals_j * K(m - p_j); K = fixed 127-radius stencil,
// 128-periodic == free-space (support radius <= 63).
// D1: blocks 0..127 build K rows self-contained (R5-validated Phase A);
//     block 128 bins the 4096 injections into a 64x64 grid (counting sort).
// D2: each measurement tests only its 3x3 neighboring bins (~9 candidates
//     instead of 4096) with the exact window test + one g_K gather per hit.

#define N_INJ   4096
#define N_MEAS  4096
#define ND      128
#define NM      65               // folded modes 0..64
#define STEPS   64
#define WRAP_M  4095
#define KST     68               // khf row stride
#define MPB     16               // measurements per block (dispatch 2)

__device__ float g_K[ND * ND];   // Green's stencil, delta at (0,0), 128-periodic
__device__ int   g_bs[4097];     // bin starts (64x64 bins of 64x64 cells)
__device__ int   g_sp[N_INJ];    // binned packed coords (ix<<12)|iy
__device__ float g_sv[N_INJ];    // binned vals

// Dispatch 1: 129 blocks x 256 threads.
__global__ __launch_bounds__(256) void build_kernel(const float* __restrict__ u_t,
                                                    const float* __restrict__ scales,
                                                    const int* __restrict__ dims,
                                                    const int* __restrict__ iix,
                                                    const int* __restrict__ iiy) {
    const int b = blockIdx.x;
    const int t = threadIdx.x;

    if (b < ND) {
        // ---- K row x=b (validated in round 5: absmax 1.86e-9) ----
        __shared__ float ctab[ND];
        __shared__ float coeff[STEPS];
        __shared__ float khf[NM * KST];
        __shared__ float Cw[NM];
        if (t < ND)    ctab[t]  = cosf(0.049087385212340517f * (float)t);
        if (t < STEPS) coeff[t] = 0.001f * sinf(0.09817477042468103f * (float)t);
        __syncthreads();

        float h[17], lam[17];
#pragma unroll
        for (int k = 0; k < 17; ++k) {
            int e = t + 256 * k; if (e > NM * NM - 1) e = NM * NM - 1;
            const int wx = e / NM, wy = e - wx * NM;
            lam[k] = 0.9f + 0.05f * (ctab[wx] + ctab[wy]);
            h[k]   = coeff[0];
        }
#pragma unroll 7
        for (int s = 1; s < STEPS; ++s) {
            const float cs = coeff[s];
#pragma unroll
            for (int k = 0; k < 17; ++k) h[k] = fmaf(h[k], lam[k], cs);
        }
#pragma unroll
        for (int k = 0; k < 17; ++k) {
            const int e = t + 256 * k;
            if (e < NM * NM) {
                const int wx = e / NM, wy = e - wx * NM;
                const float w = ((wx == 0 || wx == 64) ? 1.f : 2.f)
                              * ((wy == 0 || wy == 64) ? 1.f : 2.f) * (1.f / 16384.f);
                khf[wx * KST + wy] = h[k] * w;
            }
        }
        __syncthreads();

        if (t < NM) {                       // Cw[wy] = sum_wx khf[wx][wy] cos(wx*b)
            float acc = 0.f; int idx = 0;
#pragma unroll 5
            for (int wx = 0; wx < NM; ++wx) {
                acc = fmaf(khf[wx * KST + t], ctab[idx], acc);
                idx = (idx + b) & (ND - 1);
            }
            Cw[t] = acc;
        }
        __syncthreads();

        if (t < ND) {                       // K(b,t) = sum_wy Cw[wy] cos(wy*t)
            float acc = 0.f; int idx = 0;
#pragma unroll 5
            for (int wy = 0; wy < NM; ++wy) {
                acc = fmaf(Cw[wy], ctab[idx], acc);
                idx = (idx + t) & (ND - 1);
            }
            g_K[b * ND + t] = acc;
        }
    } else {
        // ---- block 128: bin injections (counting sort into 64x64 bins) ----
        __shared__ int cnt[4096];
        for (int k = t; k < 4096; k += 256) cnt[k] = 0;
        __syncthreads();
        for (int j = t; j < N_INJ; j += 256)
            atomicAdd(&cnt[((iix[j] >> 6) << 6) | (iiy[j] >> 6)], 1);
        __syncthreads();

        int loc[16], s = 0;
#pragma unroll
        for (int k = 0; k < 16; ++k) { loc[k] = cnt[t * 16 + k]; s += loc[k]; }
        const int lane = t & 63, wv = t >> 6;
        int x = s;
#pragma unroll
        for (int d = 1; d < 64; d <<= 1) {
            const int y = __shfl_up(x, d, 64);
            if (lane >= d) x += y;
        }
        __shared__ int wtot[4];
        if (lane == 63) wtot[wv] = x;
        __syncthreads();
        int run = x - s;                    // exclusive within wave
        for (int w = 0; w < wv; ++w) run += wtot[w];
#pragma unroll
        for (int k = 0; k < 16; ++k) {
            g_bs[t * 16 + k] = run;
            cnt[t * 16 + k]  = run;         // becomes scatter cursor
            run += loc[k];
        }
        if (t == 0) g_bs[4096] = N_INJ;
        __syncthreads();

        for (int j = t; j < N_INJ; j += 256) {
            const int ix = iix[j], iy = iiy[j];
            const int pos = atomicAdd(&cnt[((ix >> 6) << 6) | (iy >> 6)], 1);
            g_sp[pos] = (ix << 12) | iy;
            g_sv[pos] = scales[j] * u_t[dims[j]];
        }
    }
}

// Dispatch 2: 256 blocks x 256 threads; 16 threads per measurement.
// Thread k (k<9) of each group handles one of the 3x3 neighbor bins.
__global__ __launch_bounds__(256) void measure_kernel(const int* __restrict__ mix,
                                                      const int* __restrict__ miy,
                                                      float* __restrict__ out) {
    const int b = blockIdx.x;
    const int t = threadIdx.x;
    const int k = t & 15;
    const int m = (b << 4) | (t >> 4);

    const int mx = mix[m];
    const int my = miy[m];
    float acc = 0.f;
    if (k < 9) {
        const int bxlo = ((mx - 63) & WRAP_M) >> 6;
        const int bylo = ((my - 63) & WRAP_M) >> 6;
        const int bin  = (((bxlo + k % 3) & 63) << 6) | ((bylo + k / 3) & 63);
        const int lo = g_bs[bin];
        const int hi = g_bs[bin + 1];
        for (int p = lo; p < hi; ++p) {
            const int sp  = g_sp[p];
            const int a   = (mx - (sp >> 12)) & WRAP_M;
            const int c   = (my - (sp & WRAP_M)) & WRAP_M;
            if ((((a + 63) & WRAP_M) < 127) && (((c + 63) & WRAP_M) < 127))
                acc += g_sv[p] * g_K[((a & 127) << 7) | (c & 127)];
        }
    }
#pragma unroll
    for (int d = 1; d < 16; d <<= 1) acc += __shfl_xor(acc, d, 64);

    __shared__ float smacc[MPB];
    if (k == 0) smacc[t >> 4] = acc;
    __syncthreads();
    if (t < MPB) out[(b << 4) | t] = smacc[t];
}

extern "C" void kernel_launch(void* const* d_in, const int* in_sizes, int n_in,
                              void* d_out, int out_size, void* d_ws, size_t ws_size,
                              hipStream_t stream) {
    const float* u_t        = (const float*)d_in[0];
    const float* inj_scales = (const float*)d_in[1];
    const int*   inj_dims   = (const int*)d_in[2];
    const int*   inj_ix     = (const int*)d_in[3];
    const int*   inj_iy     = (const int*)d_in[4];
    const int*   meas_ix    = (const int*)d_in[5];
    const int*   meas_iy    = (const int*)d_in[6];
    float*       out        = (float*)d_out;

    hipLaunchKernelGGL(build_kernel, dim3(ND + 1), dim3(256), 0, stream,
                       u_t, inj_scales, inj_dims, inj_ix, inj_iy);
    hipLaunchKernelGGL(measure_kernel, dim3(N_MEAS / MPB), dim3(256), 0, stream,
                       meas_ix, meas_iy, out);
}